// Round 13
// baseline (240.473 us; speedup 1.0000x reference)
//
#include <hip/hip_runtime.h>
#include <cstddef>

typedef _Float16 f16;
typedef _Float16 f16x8 __attribute__((ext_vector_type(8)));
typedef _Float16 f16x4 __attribute__((ext_vector_type(4)));
typedef __fp16 fp16x2 __attribute__((ext_vector_type(2)));
typedef float f32x4 __attribute__((ext_vector_type(4)));

#define BATCH 16
#define NAGENT 1024
#define NNBR 1023
#define TSTEP 20
#define DIM 256
#define ROWS 16384
#define TH2 2500.0f
#define LOG2E 1.44269504089f

// ---- workspace layout (float offsets) — R8-proven ----
#define O_PX   0           // [16384]
#define O_PY   16384       // [16384]
#define O_H16  32768       // f16 [16384][256] (2097152 floats)
#define O_AS   2129920     // [4][16384]
#define O_AD   2195456     // [4][16384]
#define O_M    2260992     // [64]
#define O_US   2261056     // [2][4][256]
#define O_UD   2263104     // [2][4][256]
#define O_WT   2265152     // f16 [3][65536] frag-ordered: chunk ((nt*8+ks)*64+lane)*8 -> ends 2363456
#define O_ADJ  2363456     // bytes [16384][128]; byte (row, s*64+q*16+c) covers j = s*512+c*32+q*8..+7
// total 2887744 floats = 11.55 MB
// whT (in d_out): frag-order tiles [ct=16][jcg=512] x 512 f16; element e at tile-lane L =
//   wh[jcg*32 + (L>>4)*8 + e][ct*16 + (L&15)]  (8 MB, verified by element trace)

// ---------------------------------------------------------------- node embed (fused build_x): wave per row
__global__ __launch_bounds__(256) void node_embed(
    const float* __restrict__ ego, const float* __restrict__ nbr,
    const float* __restrict__ node_w, const float* __restrict__ node_b,
    const float* __restrict__ node_g, const float* __restrict__ node_beta,
    const float* __restrict__ ego_w, const float* __restrict__ ego_b,
    const float* __restrict__ ego_g, const float* __restrict__ ego_beta,
    f16* __restrict__ h16, float* __restrict__ px, float* __restrict__ py) {
    int w = threadIdx.x >> 6, lane = threadIdx.x & 63;
    int row = blockIdx.x * 4 + w;
    int b = row >> 10, n = row & 1023;
    const float* src;
    if (n == 0) src = ego + (size_t)b * TSTEP * 7 + (TSTEP - 1) * 7;
    else        src = nbr + (((size_t)b * NNBR + (n - 1)) * TSTEP + (TSTEP - 1)) * 11;
    const float *W, *bias, *g, *beta;
    if (n == 0) { W = ego_w;  bias = ego_b;  g = ego_g;  beta = ego_beta; }
    else        { W = node_w; bias = node_b; g = node_g; beta = node_beta; }
    float xv[5];
#pragma unroll
    for (int k = 0; k < 5; k++) xv[k] = src[k];
    if (lane == 0) { px[row] = xv[0]; py[row] = xv[1]; }
    int c0 = lane * 4;
    float4 bv = *(const float4*)(bias + c0);
    float acc[4] = {bv.x, bv.y, bv.z, bv.w};
#pragma unroll
    for (int k = 0; k < 5; k++) {
        float4 wv = *(const float4*)(W + (size_t)k * 256 + c0);
        acc[0] = fmaf(xv[k], wv.x, acc[0]);
        acc[1] = fmaf(xv[k], wv.y, acc[1]);
        acc[2] = fmaf(xv[k], wv.z, acc[2]);
        acc[3] = fmaf(xv[k], wv.w, acc[3]);
    }
#pragma unroll
    for (int c = 0; c < 4; c++) acc[c] = fmaxf(acc[c], 0.f);
    float s1 = acc[0] + acc[1] + acc[2] + acc[3];
    float s2 = acc[0]*acc[0] + acc[1]*acc[1] + acc[2]*acc[2] + acc[3]*acc[3];
#pragma unroll
    for (int off = 1; off < 64; off <<= 1) {
        s1 += __shfl_xor(s1, off);
        s2 += __shfl_xor(s2, off);
    }
    float mean = s1 * (1.f / 256.f);
    float var  = s2 * (1.f / 256.f) - mean * mean;
    float rstd = rsqrtf(var + 1e-5f);
    float4 gv = *(const float4*)(g + c0);
    float4 be = *(const float4*)(beta + c0);
    f16x4 o;
    o[0] = (f16)((acc[0] - mean) * rstd * gv.x + be.x);
    o[1] = (f16)((acc[1] - mean) * rstd * gv.y + be.y);
    o[2] = (f16)((acc[2] - mean) * rstd * gv.z + be.z);
    o[3] = (f16)((acc[3] - mean) * rstd * gv.w + be.w);
    *(f16x4*)(h16 + (size_t)row * 256 + c0) = o;
}

// ---------------------------------------------------------------- adjacency bitmask, layout [row][s][q][c] bytes (R8-proven)
__global__ __launch_bounds__(256) void adj_build(const float* __restrict__ px,
                                                 const float* __restrict__ py,
                                                 unsigned char* __restrict__ mask) {
    int blk = blockIdx.x;           // b*64 + ic
    int b = blk >> 6, ic = blk & 63;
    int base = b << 10;
    __shared__ float sx[1024], sy[1024];
    int t = threadIdx.x;
#pragma unroll
    for (int i = 0; i < 4; i++) {
        sx[t + i * 256] = px[base + t + i * 256];
        sy[t + i * 256] = py[base + t + i * 256];
    }
    __syncthreads();
    int i_loc = t >> 4;
    int s = (t >> 3) & 1;
    int q = (t >> 1) & 3;
    int chalf = t & 1;
    int ig = ic * 16 + i_loc;
    float xi = sx[ig], yi = sy[ig];
    unsigned int w0 = 0, w1 = 0;
#pragma unroll
    for (int cc = 0; cc < 8; cc++) {
        int c = chalf * 8 + cc;
        unsigned int byte = 0;
        int j0 = s * 512 + c * 32 + q * 8;
#pragma unroll
        for (int jj = 0; jj < 8; jj++) {
            int j = j0 + jj;
            float dx = sx[j] - xi, dy = sy[j] - yi;
            if ((dx * dx + dy * dy < TH2) || (j == ig)) byte |= 1u << jj;
        }
        if (cc < 4) w0 |= byte << (cc * 8);
        else        w1 |= byte << ((cc - 4) * 8);
    }
    uint2 v; v.x = w0; v.y = w1;
    *(uint2*)(mask + (((size_t)(base + ig)) << 7) + s * 64 + q * 16 + chalf * 8) = v;
}

// ---------------------------------------------------------------- prep: W -> frag-ordered f16 WT2 (48 blocks) + us/ud (8 blocks)
__global__ __launch_bounds__(256) void prep_weights(
    const float* __restrict__ gat_w, const float* __restrict__ proj_w,
    const float* __restrict__ asrc, const float* __restrict__ adst,
    f16* __restrict__ WT, float* __restrict__ us, float* __restrict__ ud) {
    int bid = blockIdx.x;
    int t = threadIdx.x;
    if (bid < 48) {
        int m = bid >> 4, part = bid & 15;
        const float* W = (m < 2) ? (gat_w + (size_t)m * 65536) : proj_w;
        f16* WO = WT + (size_t)m * 65536;
#pragma unroll
        for (int i = 0; i < 2; i++) {
            int chunk = part * 512 + i * 256 + t;      // [0, 8192)
            int lane = chunk & 63;
            int ksnt = chunk >> 6;
            int ks = ksnt & 7, nt = ksnt >> 3;
            int n = nt * 16 + (lane & 15);
            int k0 = ks * 32 + (lane >> 4) * 8;
            f16x8 v;
#pragma unroll
            for (int e = 0; e < 8; e++) v[e] = (f16)W[(size_t)(k0 + e) * 256 + n];
            *(f16x8*)(WO + (size_t)chunk * 8) = v;
        }
    } else {
        int blk = bid - 48;         // l*4 + h
        int l = blk >> 2, h = blk & 3;
        const float* W  = gat_w + (size_t)l * 65536 + t * 256 + h * 64;
        const float* as = asrc + l * 256 + h * 64;
        const float* ad = adst + l * 256 + h * 64;
        float s = 0.f, d = 0.f;
#pragma unroll 8
        for (int c = 0; c < 64; c++) { s = fmaf(W[c], as[c], s); d = fmaf(W[c], ad[c], d); }
        us[blk * 256 + t] = s;
        ud[blk * 256 + t] = d;
    }
}

// ---------------------------------------------------------------- f16 MFMA GEMM (32-row, frag-order B in, frag-order whT out)
__global__ __launch_bounds__(256, 4) void gemm_f16(
    const f16* __restrict__ A, const f16* __restrict__ BT2,
    f16* __restrict__ whT, float* __restrict__ outF, const float* __restrict__ bias,
    const float* __restrict__ us, const float* __restrict__ ud,
    float* __restrict__ a_sT, float* __restrict__ a_dT) {
    __shared__ f16 sA[32 * 264];
    __shared__ float sU[8 * 256];
    int t = threadIdx.x;
    int m0 = blockIdx.x * 32;
    {
        int r = t >> 3, u0 = (t & 7) * 4;
        const f16* gp = A + (size_t)(m0 + r) * 256 + u0 * 8;
        f16* lp = sA + r * 264 + u0 * 8;
#pragma unroll
        for (int u = 0; u < 4; u++)
            *(f16x8*)(lp + u * 8) = *(const f16x8*)(gp + u * 8);
    }
    if (us) {
#pragma unroll
        for (int i = 0; i < 4; i++) sU[t + i * 256] = us[t + i * 256];
#pragma unroll
        for (int i = 0; i < 4; i++) sU[1024 + t + i * 256] = ud[t + i * 256];
    }
    __syncthreads();
    int w = t >> 6, lane = t & 63, il = lane & 15, q = lane >> 4;
    int n0 = w * 64;
    f32x4 acc[2][4];
#pragma unroll
    for (int mt = 0; mt < 2; mt++)
#pragma unroll
        for (int nt = 0; nt < 4; nt++) acc[mt][nt] = (f32x4){0.f, 0.f, 0.f, 0.f};
    const f16* Bp  = BT2 + (size_t)w * 16384 + (size_t)lane * 8;
    const f16* Ap0 = sA + il * 264 + q * 8;
#pragma unroll 2
    for (int ksi = 0; ksi < 8; ksi++) {
        f16x8 a0 = *(const f16x8*)(Ap0 + ksi * 32);
        f16x8 a1 = *(const f16x8*)(Ap0 + 16 * 264 + ksi * 32);
        f16x8 b0 = *(const f16x8*)(Bp + ksi * 512);
        f16x8 b1 = *(const f16x8*)(Bp + 4096 + ksi * 512);
        f16x8 b2 = *(const f16x8*)(Bp + 8192 + ksi * 512);
        f16x8 b3 = *(const f16x8*)(Bp + 12288 + ksi * 512);
        acc[0][0] = __builtin_amdgcn_mfma_f32_16x16x32_f16(a0, b0, acc[0][0], 0, 0, 0);
        acc[0][1] = __builtin_amdgcn_mfma_f32_16x16x32_f16(a0, b1, acc[0][1], 0, 0, 0);
        acc[0][2] = __builtin_amdgcn_mfma_f32_16x16x32_f16(a0, b2, acc[0][2], 0, 0, 0);
        acc[0][3] = __builtin_amdgcn_mfma_f32_16x16x32_f16(a0, b3, acc[0][3], 0, 0, 0);
        acc[1][0] = __builtin_amdgcn_mfma_f32_16x16x32_f16(a1, b0, acc[1][0], 0, 0, 0);
        acc[1][1] = __builtin_amdgcn_mfma_f32_16x16x32_f16(a1, b1, acc[1][1], 0, 0, 0);
        acc[1][2] = __builtin_amdgcn_mfma_f32_16x16x32_f16(a1, b2, acc[1][2], 0, 0, 0);
        acc[1][3] = __builtin_amdgcn_mfma_f32_16x16x32_f16(a1, b3, acc[1][3], 0, 0, 0);
    }
    if (whT) {
        // frag-order whT: tile (ct = w*4+nt, jcg = blockIdx), element (j_local, il)
        // stored at tile*512 + ((j_local>>3)*16 + il)*8 + (j_local&7); f16x4 over regs.
        size_t tbase = ((size_t)blockIdx.x) * 512 + (size_t)(w * 4) * 512 * 512 + (size_t)(lane & 15) * 0;
#pragma unroll
        for (int mt = 0; mt < 2; mt++)
#pragma unroll
            for (int nt = 0; nt < 4; nt++) {
                f16x4 v;
#pragma unroll
                for (int reg = 0; reg < 4; reg++) v[reg] = (f16)acc[mt][nt][reg];
                size_t off = ((size_t)(w * 4 + nt) * 512 + blockIdx.x) * 512
                           + (size_t)((mt * 2 + (q >> 1)) * 16 + il) * 8 + (q & 1) * 4;
                *(f16x4*)(whT + off) = v;
            }
        (void)tbase;
    } else {
#pragma unroll
        for (int nt = 0; nt < 4; nt++) {
            float bv = bias[n0 + nt * 16 + il];
#pragma unroll
            for (int mt = 0; mt < 2; mt++)
#pragma unroll
                for (int reg = 0; reg < 4; reg++)
                    outF[(size_t)(m0 + mt * 16 + q * 4 + reg) * 256 + n0 + nt * 16 + il] =
                        acc[mt][nt][reg] + bv;
        }
    }
    if (us) {
        int r2 = t >> 3, sub = t & 7;
        int hh = sub & 3, isD = sub >> 2;
        const float* uv = sU + isD * 1024 + hh * 256;
        const f16* ar = sA + r2 * 264;
        float d0 = 0.f;
#pragma unroll 4
        for (int kk = 0; kk < 32; kk++) {
            f16x8 av = *(const f16x8*)(ar + kk * 8);
            float4 u0 = *(const float4*)(uv + kk * 8);
            float4 u1 = *(const float4*)(uv + kk * 8 + 4);
            d0 += (float)av[0] * u0.x + (float)av[1] * u0.y +
                  (float)av[2] * u0.z + (float)av[3] * u0.w +
                  (float)av[4] * u1.x + (float)av[5] * u1.y +
                  (float)av[6] * u1.z + (float)av[7] * u1.w;
        }
        float* dst = isD ? a_dT : a_sT;
        dst[(size_t)hh * ROWS + m0 + r2] = d0;
    }
}

// ---------------------------------------------------------------- per (b,h) max of a_s
__global__ __launch_bounds__(256) void reduce_max(const float* __restrict__ a_sT,
                                                  float* __restrict__ M) {
    int blk = blockIdx.x;           // b*4 + h
    int b = blk >> 2, h = blk & 3;
    const float* p = a_sT + (size_t)h * ROWS + b * NAGENT;
    int t = threadIdx.x;
    float m = fmaxf(fmaxf(p[t], p[t + 256]), fmaxf(p[t + 512], p[t + 768]));
#pragma unroll
    for (int off = 32; off > 0; off >>= 1) m = fmaxf(m, __shfl_down(m, off));
    __shared__ float red[4];
    if ((t & 63) == 0) red[t >> 6] = m;
    __syncthreads();
    if (t == 0) M[blk] = fmaxf(fmaxf(red[0], red[1]), fmaxf(red[2], red[3]));
}

// ---------------------------------------------------------------- fused GAT attention: 32 i-rows/block, 8 waves = (head, j-half)
// whT in frag order -> all 4 B-frag loads are coalesced 1 KB wave-loads.
// blockIdx XCD-swizzled so each batch stays on one XCD's L2.
__global__ __launch_bounds__(512, 4) void gat_attn(
    const f16* __restrict__ whT, const float* __restrict__ a_sT,
    const float* __restrict__ a_dT, const unsigned char* __restrict__ mask,
    const float* __restrict__ M, const float* __restrict__ gat_b,
    f16* __restrict__ h16out) {
    __shared__ f32x4 comb[10][4][64];
    int t = threadIdx.x;
    int w = t >> 6, lane = t & 63;
    int h = w & 3, s = w >> 2;
    int B = blockIdx.x;                 // XCD swizzle: batch b pinned to XCD B%8
    int slot = B >> 3;
    int b = (B & 7) + 8 * (slot >> 5);
    int i0 = (slot & 31) << 5;          // 32 i-rows per block
    int base = b << 10;
    int il = lane & 15, q = lane >> 4;
    int ig0 = i0 + il, ig1 = i0 + 16 + il;

    float Mh = M[b * 4 + h];
    float adv0 = a_dT[(size_t)h * ROWS + base + ig0];
    float adv1 = a_dT[(size_t)h * ROWS + base + ig1];
    float mz0 = Mh + adv0, mz1 = Mh + adv1;
    float mi0 = fmaxf(mz0, 0.2f * mz0), mi1 = fmaxf(mz1, 0.2f * mz1);
    float nm0 = -mi0 * LOG2E, nm1 = -mi1 * LOG2E;

    uint4 mq0 = *(const uint4*)(mask + (((size_t)(base + ig0)) << 7) + s * 64 + q * 16);
    uint4 mq1 = *(const uint4*)(mask + (((size_t)(base + ig1)) << 7) + s * 64 + q * 16);
    unsigned int mw0[4] = {mq0.x, mq0.y, mq0.z, mq0.w};
    unsigned int mw1[4] = {mq1.x, mq1.y, mq1.z, mq1.w};

    f32x4 acc[2][5];
#pragma unroll
    for (int mt = 0; mt < 2; mt++)
#pragma unroll
        for (int nt = 0; nt < 5; nt++) acc[mt][nt] = (f32x4){0.f, 0.f, 0.f, 0.f};
    f16x8 ones;
#pragma unroll
    for (int j = 0; j < 8; j++) ones[j] = (f16)1.f;

    // frag-order whT base: tiles (ct = h*4+nt, jcg = b*32 + s*16 + c)
    const f16*   wpb = whT + ((size_t)(h * 4) * 512 + b * 32 + s * 16) * 512 + (size_t)lane * 8;
    const float* asp = a_sT + (size_t)h * ROWS + base + (s << 9) + q * 8;

    for (int c = 0; c < 16; ++c) {
        f16x8 b0 = *(const f16x8*)(wpb + c * 512);
        f16x8 b1 = *(const f16x8*)(wpb + 262144 + c * 512);
        f16x8 b2 = *(const f16x8*)(wpb + 524288 + c * 512);
        f16x8 b3 = *(const f16x8*)(wpb + 786432 + c * 512);
        int j0 = c * 32;
        float4 as0 = *(const float4*)(asp + j0);
        float4 as1 = *(const float4*)(asp + j0 + 4);
        unsigned int mb0 = (mw0[c >> 2] >> ((c & 3) * 8)) & 255u;
        unsigned int mb1 = (mw1[c >> 2] >> ((c & 3) * 8)) & 255u;
        float asv[8] = {as0.x, as0.y, as0.z, as0.w, as1.x, as1.y, as1.z, as1.w};
        union { f16x8 v; fp16x2 hp[4]; } u0, u1;
#pragma unroll
        for (int jp = 0; jp < 4; ++jp) {
            float va = asv[2 * jp], vb = asv[2 * jp + 1];
            float za = va + adv0, zb = vb + adv0;
            float zc = va + adv1, zd = vb + adv1;
            float sa = fmaxf(za, 0.2f * za), sb = fmaxf(zb, 0.2f * zb);
            float sc_ = fmaxf(zc, 0.2f * zc), sd = fmaxf(zd, 0.2f * zd);
            float ea = exp2f(fmaf(sa, LOG2E, nm0));
            float eb = exp2f(fmaf(sb, LOG2E, nm0));
            float ec = exp2f(fmaf(sc_, LOG2E, nm1));
            float ed = exp2f(fmaf(sd, LOG2E, nm1));
            ea = ((mb0 >> (2 * jp)) & 1u) ? ea : 0.f;
            eb = ((mb0 >> (2 * jp + 1)) & 1u) ? eb : 0.f;
            ec = ((mb1 >> (2 * jp)) & 1u) ? ec : 0.f;
            ed = ((mb1 >> (2 * jp + 1)) & 1u) ? ed : 0.f;
            u0.hp[jp] = __builtin_amdgcn_cvt_pkrtz(ea, eb);
            u1.hp[jp] = __builtin_amdgcn_cvt_pkrtz(ec, ed);
        }
        f16x8 afr0 = u0.v, afr1 = u1.v;
        acc[0][0] = __builtin_amdgcn_mfma_f32_16x16x32_f16(afr0, b0, acc[0][0], 0, 0, 0);
        acc[1][0] = __builtin_amdgcn_mfma_f32_16x16x32_f16(afr1, b0, acc[1][0], 0, 0, 0);
        acc[0][1] = __builtin_amdgcn_mfma_f32_16x16x32_f16(afr0, b1, acc[0][1], 0, 0, 0);
        acc[1][1] = __builtin_amdgcn_mfma_f32_16x16x32_f16(afr1, b1, acc[1][1], 0, 0, 0);
        acc[0][2] = __builtin_amdgcn_mfma_f32_16x16x32_f16(afr0, b2, acc[0][2], 0, 0, 0);
        acc[1][2] = __builtin_amdgcn_mfma_f32_16x16x32_f16(afr1, b2, acc[1][2], 0, 0, 0);
        acc[0][3] = __builtin_amdgcn_mfma_f32_16x16x32_f16(afr0, b3, acc[0][3], 0, 0, 0);
        acc[1][3] = __builtin_amdgcn_mfma_f32_16x16x32_f16(afr1, b3, acc[1][3], 0, 0, 0);
        acc[0][4] = __builtin_amdgcn_mfma_f32_16x16x32_f16(afr0, ones, acc[0][4], 0, 0, 0);
        acc[1][4] = __builtin_amdgcn_mfma_f32_16x16x32_f16(afr1, ones, acc[1][4], 0, 0, 0);
    }
    if (s == 1) {
#pragma unroll
        for (int mt = 0; mt < 2; mt++)
#pragma unroll
            for (int nt = 0; nt < 5; nt++) comb[mt * 5 + nt][h][lane] = acc[mt][nt];
    }
    __syncthreads();
    if (s == 0) {
#pragma unroll
        for (int mt = 0; mt < 2; mt++)
#pragma unroll
            for (int nt = 0; nt < 5; nt++) acc[mt][nt] += comb[mt * 5 + nt][h][lane];
        float b0v = gat_b[h * 64 + il];
        float b1v = gat_b[h * 64 + 16 + il];
        float b2v = gat_b[h * 64 + 32 + il];
        float b3v = gat_b[h * 64 + 48 + il];
#pragma unroll
        for (int mt = 0; mt < 2; mt++) {
#pragma unroll
            for (int reg = 0; reg < 4; ++reg) {
                float inv = 1.f / acc[mt][4][reg];
                size_t ro = (size_t)(base + i0 + mt * 16 + q * 4 + reg) * DIM + h * 64 + il;
                h16out[ro +  0] = (f16)fmaxf(fmaf(acc[mt][0][reg], inv, b0v), 0.f);
                h16out[ro + 16] = (f16)fmaxf(fmaf(acc[mt][1][reg], inv, b1v), 0.f);
                h16out[ro + 32] = (f16)fmaxf(fmaf(acc[mt][2][reg], inv, b2v), 0.f);
                h16out[ro + 48] = (f16)fmaxf(fmaf(acc[mt][3][reg], inv, b3v), 0.f);
            }
        }
    }
}

// ---------------------------------------------------------------- mask zeros
__global__ void zero_mask(float* __restrict__ p) {
    p[blockIdx.x * 256 + threadIdx.x] = 0.f;
}

// ---------------------------------------------------------------- launch
extern "C" void kernel_launch(void* const* d_in, const int* in_sizes, int n_in,
                              void* d_out, int out_size, void* d_ws, size_t ws_size,
                              hipStream_t stream) {
    const float* ego       = (const float*)d_in[0];
    const float* nbr       = (const float*)d_in[1];
    const float* node_w    = (const float*)d_in[2];
    const float* node_b    = (const float*)d_in[3];
    const float* node_g    = (const float*)d_in[4];
    const float* node_beta = (const float*)d_in[5];
    const float* ego_w     = (const float*)d_in[6];
    const float* ego_b     = (const float*)d_in[7];
    const float* ego_g     = (const float*)d_in[8];
    const float* ego_beta  = (const float*)d_in[9];
    const float* gat_w     = (const float*)d_in[10];
    const float* gat_asrc  = (const float*)d_in[11];
    const float* gat_adst  = (const float*)d_in[12];
    const float* gat_bias  = (const float*)d_in[13];
    const float* proj_w    = (const float*)d_in[14];
    const float* proj_b    = (const float*)d_in[15];

    float* out = (float*)d_out;
    float* ws  = (float*)d_ws;
    float* px   = ws + O_PX;
    float* py   = ws + O_PY;
    f16*   h16  = (f16*)(ws + O_H16);
    float* asT  = ws + O_AS;
    float* adT  = ws + O_AD;
    float* Mmax = ws + O_M;
    float* us   = ws + O_US;
    float* ud   = ws + O_UD;
    f16*   WT   = (f16*)(ws + O_WT);
    unsigned char* adj = (unsigned char*)(ws + O_ADJ);
    f16*   whT  = (f16*)d_out;      // 8 MB frag-order scratch in d_out; final gemm overwrites last

    node_embed<<<4096, 256, 0, stream>>>(ego, nbr, node_w, node_b, node_g, node_beta,
                                         ego_w, ego_b, ego_g, ego_beta, h16, px, py);
    adj_build<<<1024, 256, 0, stream>>>(px, py, adj);
    prep_weights<<<56, 256, 0, stream>>>(gat_w, proj_w, gat_asrc, gat_adst, WT, us, ud);
    for (int l = 0; l < 2; l++) {
        gemm_f16<<<512, 256, 0, stream>>>(h16, WT + (size_t)l * 65536, whT, nullptr, nullptr,
                                          us + l * 1024, ud + l * 1024, asT, adT);
        reduce_max<<<64, 256, 0, stream>>>(asT, Mmax);
        gat_attn<<<512, 512, 0, stream>>>(whT, asT, adT, adj, Mmax,
                                          gat_bias + l * 256, h16);
    }
    gemm_f16<<<512, 256, 0, stream>>>(h16, WT + (size_t)2 * 65536, nullptr, out, proj_b,
                                      nullptr, nullptr, nullptr, nullptr);
    zero_mask<<<64, 256, 0, stream>>>(out + (size_t)ROWS * DIM);
}

// Round 15
// 228.078 us; speedup vs baseline: 1.0543x; 1.0543x over previous
//
#include <hip/hip_runtime.h>
#include <cstddef>

typedef _Float16 f16;
typedef _Float16 f16x8 __attribute__((ext_vector_type(8)));
typedef _Float16 f16x4 __attribute__((ext_vector_type(4)));
typedef __fp16 fp16x2 __attribute__((ext_vector_type(2)));
typedef float f32x4 __attribute__((ext_vector_type(4)));

#define BATCH 16
#define NAGENT 1024
#define NNBR 1023
#define TSTEP 20
#define DIM 256
#define ROWS 16384
#define TH2 2500.0f
#define LOG2E 1.44269504089f

// ---- workspace layout (float offsets) — sizes re-derived from bytes ----
#define O_PX   0           // [16384] floats
#define O_PY   16384       // [16384]
#define O_H16  32768       // f16 [16384][256] = 8 MB = 2097152 floats -> ends 2129920
#define O_AS   2129920     // [4][16384] floats -> ends 2195456
#define O_AD   2195456     // -> ends 2260992
#define O_M    2260992     // [64] -> 2261056
#define O_US   2261056     // [2][4][256] -> 2263104
#define O_UD   2263104     // -> 2265152
#define O_WT   2265152     // f16 [3][65536] = 196608 f16 = 98304 floats -> ends 2363456
#define O_ADJ  2363456     // bytes [16384][128] = 2 MB = 524288 floats -> ends 2887744
#define O_EA   2887744     // [4][16384] floats -> ends 2953280
#define O_EB   2953280     // [4][16384] floats -> ends 3018816
// total 3018816 floats = 12.08 MB (< 17.6 MB proven available)
// whT (in d_out): frag-order tiles [ct=16][jcg=512] x 512 f16 (R13-verified)

// ---------------------------------------------------------------- node embed (fused build_x): wave per row
__global__ __launch_bounds__(256) void node_embed(
    const float* __restrict__ ego, const float* __restrict__ nbr,
    const float* __restrict__ node_w, const float* __restrict__ node_b,
    const float* __restrict__ node_g, const float* __restrict__ node_beta,
    const float* __restrict__ ego_w, const float* __restrict__ ego_b,
    const float* __restrict__ ego_g, const float* __restrict__ ego_beta,
    f16* __restrict__ h16, float* __restrict__ px, float* __restrict__ py) {
    int w = threadIdx.x >> 6, lane = threadIdx.x & 63;
    int row = blockIdx.x * 4 + w;
    int b = row >> 10, n = row & 1023;
    const float* src;
    if (n == 0) src = ego + (size_t)b * TSTEP * 7 + (TSTEP - 1) * 7;
    else        src = nbr + (((size_t)b * NNBR + (n - 1)) * TSTEP + (TSTEP - 1)) * 11;
    const float *W, *bias, *g, *beta;
    if (n == 0) { W = ego_w;  bias = ego_b;  g = ego_g;  beta = ego_beta; }
    else        { W = node_w; bias = node_b; g = node_g; beta = node_beta; }
    float xv[5];
#pragma unroll
    for (int k = 0; k < 5; k++) xv[k] = src[k];
    if (lane == 0) { px[row] = xv[0]; py[row] = xv[1]; }
    int c0 = lane * 4;
    float4 bv = *(const float4*)(bias + c0);
    float acc[4] = {bv.x, bv.y, bv.z, bv.w};
#pragma unroll
    for (int k = 0; k < 5; k++) {
        float4 wv = *(const float4*)(W + (size_t)k * 256 + c0);
        acc[0] = fmaf(xv[k], wv.x, acc[0]);
        acc[1] = fmaf(xv[k], wv.y, acc[1]);
        acc[2] = fmaf(xv[k], wv.z, acc[2]);
        acc[3] = fmaf(xv[k], wv.w, acc[3]);
    }
#pragma unroll
    for (int c = 0; c < 4; c++) acc[c] = fmaxf(acc[c], 0.f);
    float s1 = acc[0] + acc[1] + acc[2] + acc[3];
    float s2 = acc[0]*acc[0] + acc[1]*acc[1] + acc[2]*acc[2] + acc[3]*acc[3];
#pragma unroll
    for (int off = 1; off < 64; off <<= 1) {
        s1 += __shfl_xor(s1, off);
        s2 += __shfl_xor(s2, off);
    }
    float mean = s1 * (1.f / 256.f);
    float var  = s2 * (1.f / 256.f) - mean * mean;
    float rstd = rsqrtf(var + 1e-5f);
    float4 gv = *(const float4*)(g + c0);
    float4 be = *(const float4*)(beta + c0);
    f16x4 o;
    o[0] = (f16)((acc[0] - mean) * rstd * gv.x + be.x);
    o[1] = (f16)((acc[1] - mean) * rstd * gv.y + be.y);
    o[2] = (f16)((acc[2] - mean) * rstd * gv.z + be.z);
    o[3] = (f16)((acc[3] - mean) * rstd * gv.w + be.w);
    *(f16x4*)(h16 + (size_t)row * 256 + c0) = o;
}

// ---------------------------------------------------------------- adjacency bitmask, layout [row][s][q][c] bytes (R8-proven)
__global__ __launch_bounds__(256) void adj_build(const float* __restrict__ px,
                                                 const float* __restrict__ py,
                                                 unsigned char* __restrict__ mask) {
    int blk = blockIdx.x;           // b*64 + ic
    int b = blk >> 6, ic = blk & 63;
    int base = b << 10;
    __shared__ float sx[1024], sy[1024];
    int t = threadIdx.x;
#pragma unroll
    for (int i = 0; i < 4; i++) {
        sx[t + i * 256] = px[base + t + i * 256];
        sy[t + i * 256] = py[base + t + i * 256];
    }
    __syncthreads();
    int i_loc = t >> 4;
    int s = (t >> 3) & 1;
    int q = (t >> 1) & 3;
    int chalf = t & 1;
    int ig = ic * 16 + i_loc;
    float xi = sx[ig], yi = sy[ig];
    unsigned int w0 = 0, w1 = 0;
#pragma unroll
    for (int cc = 0; cc < 8; cc++) {
        int c = chalf * 8 + cc;
        unsigned int byte = 0;
        int j0 = s * 512 + c * 32 + q * 8;
#pragma unroll
        for (int jj = 0; jj < 8; jj++) {
            int j = j0 + jj;
            float dx = sx[j] - xi, dy = sy[j] - yi;
            if ((dx * dx + dy * dy < TH2) || (j == ig)) byte |= 1u << jj;
        }
        if (cc < 4) w0 |= byte << (cc * 8);
        else        w1 |= byte << ((cc - 4) * 8);
    }
    uint2 v; v.x = w0; v.y = w1;
    *(uint2*)(mask + (((size_t)(base + ig)) << 7) + s * 64 + q * 16 + chalf * 8) = v;
}

// ---------------------------------------------------------------- prep: W -> frag-ordered f16 WT2 (48 blocks) + us/ud (8 blocks)
__global__ __launch_bounds__(256) void prep_weights(
    const float* __restrict__ gat_w, const float* __restrict__ proj_w,
    const float* __restrict__ asrc, const float* __restrict__ adst,
    f16* __restrict__ WT, float* __restrict__ us, float* __restrict__ ud) {
    int bid = blockIdx.x;
    int t = threadIdx.x;
    if (bid < 48) {
        int m = bid >> 4, part = bid & 15;
        const float* W = (m < 2) ? (gat_w + (size_t)m * 65536) : proj_w;
        f16* WO = WT + (size_t)m * 65536;
#pragma unroll
        for (int i = 0; i < 2; i++) {
            int chunk = part * 512 + i * 256 + t;      // [0, 8192)
            int lane = chunk & 63;
            int ksnt = chunk >> 6;
            int ks = ksnt & 7, nt = ksnt >> 3;
            int n = nt * 16 + (lane & 15);
            int k0 = ks * 32 + (lane >> 4) * 8;
            f16x8 v;
#pragma unroll
            for (int e = 0; e < 8; e++) v[e] = (f16)W[(size_t)(k0 + e) * 256 + n];
            *(f16x8*)(WO + (size_t)chunk * 8) = v;
        }
    } else {
        int blk = bid - 48;         // l*4 + h
        int l = blk >> 2, h = blk & 3;
        const float* W  = gat_w + (size_t)l * 65536 + t * 256 + h * 64;
        const float* as = asrc + l * 256 + h * 64;
        const float* ad = adst + l * 256 + h * 64;
        float s = 0.f, d = 0.f;
#pragma unroll 8
        for (int c = 0; c < 64; c++) { s = fmaf(W[c], as[c], s); d = fmaf(W[c], ad[c], d); }
        us[blk * 256 + t] = s;
        ud[blk * 256 + t] = d;
    }
}

// ---------------------------------------------------------------- f16 MFMA GEMM (32-row, frag-order B in, frag-order whT out)
__global__ __launch_bounds__(256, 4) void gemm_f16(
    const f16* __restrict__ A, const f16* __restrict__ BT2,
    f16* __restrict__ whT, float* __restrict__ outF, const float* __restrict__ bias,
    const float* __restrict__ us, const float* __restrict__ ud,
    float* __restrict__ a_sT, float* __restrict__ a_dT) {
    __shared__ f16 sA[32 * 264];
    __shared__ float sU[8 * 256];
    int t = threadIdx.x;
    int m0 = blockIdx.x * 32;
    {
        int r = t >> 3, u0 = (t & 7) * 4;
        const f16* gp = A + (size_t)(m0 + r) * 256 + u0 * 8;
        f16* lp = sA + r * 264 + u0 * 8;
#pragma unroll
        for (int u = 0; u < 4; u++)
            *(f16x8*)(lp + u * 8) = *(const f16x8*)(gp + u * 8);
    }
    if (us) {
#pragma unroll
        for (int i = 0; i < 4; i++) sU[t + i * 256] = us[t + i * 256];
#pragma unroll
        for (int i = 0; i < 4; i++) sU[1024 + t + i * 256] = ud[t + i * 256];
    }
    __syncthreads();
    int w = t >> 6, lane = t & 63, il = lane & 15, q = lane >> 4;
    int n0 = w * 64;
    f32x4 acc[2][4];
#pragma unroll
    for (int mt = 0; mt < 2; mt++)
#pragma unroll
        for (int nt = 0; nt < 4; nt++) acc[mt][nt] = (f32x4){0.f, 0.f, 0.f, 0.f};
    const f16* Bp  = BT2 + (size_t)w * 16384 + (size_t)lane * 8;
    const f16* Ap0 = sA + il * 264 + q * 8;
#pragma unroll 2
    for (int ksi = 0; ksi < 8; ksi++) {
        f16x8 a0 = *(const f16x8*)(Ap0 + ksi * 32);
        f16x8 a1 = *(const f16x8*)(Ap0 + 16 * 264 + ksi * 32);
        f16x8 b0 = *(const f16x8*)(Bp + ksi * 512);
        f16x8 b1 = *(const f16x8*)(Bp + 4096 + ksi * 512);
        f16x8 b2 = *(const f16x8*)(Bp + 8192 + ksi * 512);
        f16x8 b3 = *(const f16x8*)(Bp + 12288 + ksi * 512);
        acc[0][0] = __builtin_amdgcn_mfma_f32_16x16x32_f16(a0, b0, acc[0][0], 0, 0, 0);
        acc[0][1] = __builtin_amdgcn_mfma_f32_16x16x32_f16(a0, b1, acc[0][1], 0, 0, 0);
        acc[0][2] = __builtin_amdgcn_mfma_f32_16x16x32_f16(a0, b2, acc[0][2], 0, 0, 0);
        acc[0][3] = __builtin_amdgcn_mfma_f32_16x16x32_f16(a0, b3, acc[0][3], 0, 0, 0);
        acc[1][0] = __builtin_amdgcn_mfma_f32_16x16x32_f16(a1, b0, acc[1][0], 0, 0, 0);
        acc[1][1] = __builtin_amdgcn_mfma_f32_16x16x32_f16(a1, b1, acc[1][1], 0, 0, 0);
        acc[1][2] = __builtin_amdgcn_mfma_f32_16x16x32_f16(a1, b2, acc[1][2], 0, 0, 0);
        acc[1][3] = __builtin_amdgcn_mfma_f32_16x16x32_f16(a1, b3, acc[1][3], 0, 0, 0);
    }
    if (whT) {
#pragma unroll
        for (int mt = 0; mt < 2; mt++)
#pragma unroll
            for (int nt = 0; nt < 4; nt++) {
                f16x4 v;
#pragma unroll
                for (int reg = 0; reg < 4; reg++) v[reg] = (f16)acc[mt][nt][reg];
                size_t off = ((size_t)(w * 4 + nt) * 512 + blockIdx.x) * 512
                           + (size_t)((mt * 2 + (q >> 1)) * 16 + il) * 8 + (q & 1) * 4;
                *(f16x4*)(whT + off) = v;
            }
    } else {
#pragma unroll
        for (int nt = 0; nt < 4; nt++) {
            float bv = bias[n0 + nt * 16 + il];
#pragma unroll
            for (int mt = 0; mt < 2; mt++)
#pragma unroll
                for (int reg = 0; reg < 4; reg++)
                    outF[(size_t)(m0 + mt * 16 + q * 4 + reg) * 256 + n0 + nt * 16 + il] =
                        acc[mt][nt][reg] + bv;
        }
    }
    if (us) {
        int r2 = t >> 3, sub = t & 7;
        int hh = sub & 3, isD = sub >> 2;
        const float* uv = sU + isD * 1024 + hh * 256;
        const f16* ar = sA + r2 * 264;
        float d0 = 0.f;
#pragma unroll 4
        for (int kk = 0; kk < 32; kk++) {
            f16x8 av = *(const f16x8*)(ar + kk * 8);
            float4 u0 = *(const float4*)(uv + kk * 8);
            float4 u1 = *(const float4*)(uv + kk * 8 + 4);
            d0 += (float)av[0] * u0.x + (float)av[1] * u0.y +
                  (float)av[2] * u0.z + (float)av[3] * u0.w +
                  (float)av[4] * u1.x + (float)av[5] * u1.y +
                  (float)av[6] * u1.z + (float)av[7] * u1.w;
        }
        float* dst = isD ? a_dT : a_sT;
        dst[(size_t)hh * ROWS + m0 + r2] = d0;
    }
}

// ---------------------------------------------------------------- softmax prep: per (b,h) max + EA/EB = exp(as-Mh), exp(0.2(as-Mh))
__global__ __launch_bounds__(256) void softmax_prep(const float* __restrict__ a_sT,
                                                    float* __restrict__ M,
                                                    float* __restrict__ EA,
                                                    float* __restrict__ EB) {
    int blk = blockIdx.x;           // b*4 + h
    int b = blk >> 2, h = blk & 3;
    size_t off = (size_t)h * ROWS + b * NAGENT;
    const float* p = a_sT + off;
    int t = threadIdx.x;
    float v0 = p[t], v1 = p[t + 256], v2 = p[t + 512], v3 = p[t + 768];
    float m = fmaxf(fmaxf(v0, v1), fmaxf(v2, v3));
#pragma unroll
    for (int o = 32; o > 0; o >>= 1) m = fmaxf(m, __shfl_down(m, o));
    __shared__ float red[4];
    __shared__ float mfin;
    if ((t & 63) == 0) red[t >> 6] = m;
    __syncthreads();
    if (t == 0) {
        float mm = fmaxf(fmaxf(red[0], red[1]), fmaxf(red[2], red[3]));
        M[blk] = mm;
        mfin = mm;
    }
    __syncthreads();
    float Mh = mfin;
    float* ea = EA + off;
    float* eb = EB + off;
    ea[t]       = exp2f((v0 - Mh) * LOG2E);
    ea[t + 256] = exp2f((v1 - Mh) * LOG2E);
    ea[t + 512] = exp2f((v2 - Mh) * LOG2E);
    ea[t + 768] = exp2f((v3 - Mh) * LOG2E);
    eb[t]       = exp2f(0.2f * (v0 - Mh) * LOG2E);
    eb[t + 256] = exp2f(0.2f * (v1 - Mh) * LOG2E);
    eb[t + 512] = exp2f(0.2f * (v2 - Mh) * LOG2E);
    eb[t + 768] = exp2f(0.2f * (v3 - Mh) * LOG2E);
}

// ---------------------------------------------------------------- fused GAT attention: exp-free inner loop
// p = adj ? (z>0 ? EA_j*FA_i : EB_j*FB_i) : 0   (equals exp(leaky(z)-m_i) in both branches)
__global__ __launch_bounds__(512, 4) void gat_attn(
    const f16* __restrict__ whT, const float* __restrict__ a_sT,
    const float* __restrict__ a_dT, const float* __restrict__ EA,
    const float* __restrict__ EB, const unsigned char* __restrict__ mask,
    const float* __restrict__ M, const float* __restrict__ gat_b,
    f16* __restrict__ h16out) {
    __shared__ f32x4 comb[10][4][64];
    int t = threadIdx.x;
    int w = t >> 6, lane = t & 63;
    int h = w & 3, s = w >> 2;
    int B = blockIdx.x;                 // XCD swizzle: batch b pinned to XCD B%8
    int slot = B >> 3;
    int b = (B & 7) + 8 * (slot >> 5);
    int i0 = (slot & 31) << 5;
    int base = b << 10;
    int il = lane & 15, q = lane >> 4;
    int ig0 = i0 + il, ig1 = i0 + 16 + il;

    float Mh = M[b * 4 + h];
    float adv0 = a_dT[(size_t)h * ROWS + base + ig0];
    float adv1 = a_dT[(size_t)h * ROWS + base + ig1];
    float mz0 = Mh + adv0, mz1 = Mh + adv1;
    float mi0 = fmaxf(mz0, 0.2f * mz0), mi1 = fmaxf(mz1, 0.2f * mz1);
    float fa0 = exp2f((mz0 - mi0) * LOG2E);
    float fb0 = exp2f((0.2f * mz0 - mi0) * LOG2E);
    float fa1 = exp2f((mz1 - mi1) * LOG2E);
    float fb1 = exp2f((0.2f * mz1 - mi1) * LOG2E);
    float nadv0 = -adv0, nadv1 = -adv1;

    uint4 mq0 = *(const uint4*)(mask + (((size_t)(base + ig0)) << 7) + s * 64 + q * 16);
    uint4 mq1 = *(const uint4*)(mask + (((size_t)(base + ig1)) << 7) + s * 64 + q * 16);
    unsigned int mw0[4] = {mq0.x, mq0.y, mq0.z, mq0.w};
    unsigned int mw1[4] = {mq1.x, mq1.y, mq1.z, mq1.w};

    f32x4 acc[2][5];
#pragma unroll
    for (int mt = 0; mt < 2; mt++)
#pragma unroll
        for (int nt = 0; nt < 5; nt++) acc[mt][nt] = (f32x4){0.f, 0.f, 0.f, 0.f};
    f16x8 ones;
#pragma unroll
    for (int j = 0; j < 8; j++) ones[j] = (f16)1.f;

    const f16*   wpb = whT + ((size_t)(h * 4) * 512 + b * 32 + s * 16) * 512 + (size_t)lane * 8;
    size_t joff = (size_t)h * ROWS + base + (s << 9) + q * 8;
    const float* asp = a_sT + joff;
    const float* eap = EA + joff;
    const float* ebp = EB + joff;

    for (int c = 0; c < 16; ++c) {
        f16x8 b0 = *(const f16x8*)(wpb + c * 512);
        f16x8 b1 = *(const f16x8*)(wpb + 262144 + c * 512);
        f16x8 b2 = *(const f16x8*)(wpb + 524288 + c * 512);
        f16x8 b3 = *(const f16x8*)(wpb + 786432 + c * 512);
        int j0 = c * 32;
        float4 as0 = *(const float4*)(asp + j0);
        float4 as1 = *(const float4*)(asp + j0 + 4);
        float4 ea0 = *(const float4*)(eap + j0);
        float4 ea1 = *(const float4*)(eap + j0 + 4);
        float4 eb0 = *(const float4*)(ebp + j0);
        float4 eb1 = *(const float4*)(ebp + j0 + 4);
        unsigned int mb0 = (mw0[c >> 2] >> ((c & 3) * 8)) & 255u;
        unsigned int mb1 = (mw1[c >> 2] >> ((c & 3) * 8)) & 255u;
        float asv[8] = {as0.x, as0.y, as0.z, as0.w, as1.x, as1.y, as1.z, as1.w};
        float eav[8] = {ea0.x, ea0.y, ea0.z, ea0.w, ea1.x, ea1.y, ea1.z, ea1.w};
        float ebv[8] = {eb0.x, eb0.y, eb0.z, eb0.w, eb1.x, eb1.y, eb1.z, eb1.w};
        union { f16x8 v; fp16x2 hp[4]; } u0, u1;
#pragma unroll
        for (int jp = 0; jp < 4; ++jp) {
            int ja = 2 * jp, jb = 2 * jp + 1;
            float pa0 = ((mb0 >> ja) & 1u) ? ((asv[ja] > nadv0) ? eav[ja] * fa0 : ebv[ja] * fb0) : 0.f;
            float pb0 = ((mb0 >> jb) & 1u) ? ((asv[jb] > nadv0) ? eav[jb] * fa0 : ebv[jb] * fb0) : 0.f;
            float pa1 = ((mb1 >> ja) & 1u) ? ((asv[ja] > nadv1) ? eav[ja] * fa1 : ebv[ja] * fb1) : 0.f;
            float pb1 = ((mb1 >> jb) & 1u) ? ((asv[jb] > nadv1) ? eav[jb] * fa1 : ebv[jb] * fb1) : 0.f;
            u0.hp[jp] = __builtin_amdgcn_cvt_pkrtz(pa0, pb0);
            u1.hp[jp] = __builtin_amdgcn_cvt_pkrtz(pa1, pb1);
        }
        f16x8 afr0 = u0.v, afr1 = u1.v;
        acc[0][0] = __builtin_amdgcn_mfma_f32_16x16x32_f16(afr0, b0, acc[0][0], 0, 0, 0);
        acc[1][0] = __builtin_amdgcn_mfma_f32_16x16x32_f16(afr1, b0, acc[1][0], 0, 0, 0);
        acc[0][1] = __builtin_amdgcn_mfma_f32_16x16x32_f16(afr0, b1, acc[0][1], 0, 0, 0);
        acc[1][1] = __builtin_amdgcn_mfma_f32_16x16x32_f16(afr1, b1, acc[1][1], 0, 0, 0);
        acc[0][2] = __builtin_amdgcn_mfma_f32_16x16x32_f16(afr0, b2, acc[0][2], 0, 0, 0);
        acc[1][2] = __builtin_amdgcn_mfma_f32_16x16x32_f16(afr1, b2, acc[1][2], 0, 0, 0);
        acc[0][3] = __builtin_amdgcn_mfma_f32_16x16x32_f16(afr0, b3, acc[0][3], 0, 0, 0);
        acc[1][3] = __builtin_amdgcn_mfma_f32_16x16x32_f16(afr1, b3, acc[1][3], 0, 0, 0);
        acc[0][4] = __builtin_amdgcn_mfma_f32_16x16x32_f16(afr0, ones, acc[0][4], 0, 0, 0);
        acc[1][4] = __builtin_amdgcn_mfma_f32_16x16x32_f16(afr1, ones, acc[1][4], 0, 0, 0);
    }
    if (s == 1) {
#pragma unroll
        for (int mt = 0; mt < 2; mt++)
#pragma unroll
            for (int nt = 0; nt < 5; nt++) comb[mt * 5 + nt][h][lane] = acc[mt][nt];
    }
    __syncthreads();
    if (s == 0) {
#pragma unroll
        for (int mt = 0; mt < 2; mt++)
#pragma unroll
            for (int nt = 0; nt < 5; nt++) acc[mt][nt] += comb[mt * 5 + nt][h][lane];
        float b0v = gat_b[h * 64 + il];
        float b1v = gat_b[h * 64 + 16 + il];
        float b2v = gat_b[h * 64 + 32 + il];
        float b3v = gat_b[h * 64 + 48 + il];
#pragma unroll
        for (int mt = 0; mt < 2; mt++) {
#pragma unroll
            for (int reg = 0; reg < 4; ++reg) {
                float inv = 1.f / acc[mt][4][reg];
                size_t ro = (size_t)(base + i0 + mt * 16 + q * 4 + reg) * DIM + h * 64 + il;
                h16out[ro +  0] = (f16)fmaxf(fmaf(acc[mt][0][reg], inv, b0v), 0.f);
                h16out[ro + 16] = (f16)fmaxf(fmaf(acc[mt][1][reg], inv, b1v), 0.f);
                h16out[ro + 32] = (f16)fmaxf(fmaf(acc[mt][2][reg], inv, b2v), 0.f);
                h16out[ro + 48] = (f16)fmaxf(fmaf(acc[mt][3][reg], inv, b3v), 0.f);
            }
        }
    }
}

// ---------------------------------------------------------------- mask zeros
__global__ void zero_mask(float* __restrict__ p) {
    p[blockIdx.x * 256 + threadIdx.x] = 0.f;
}

// ---------------------------------------------------------------- launch
extern "C" void kernel_launch(void* const* d_in, const int* in_sizes, int n_in,
                              void* d_out, int out_size, void* d_ws, size_t ws_size,
                              hipStream_t stream) {
    const float* ego       = (const float*)d_in[0];
    const float* nbr       = (const float*)d_in[1];
    const float* node_w    = (const float*)d_in[2];
    const float* node_b    = (const float*)d_in[3];
    const float* node_g    = (const float*)d_in[4];
    const float* node_beta = (const float*)d_in[5];
    const float* ego_w     = (const float*)d_in[6];
    const float* ego_b     = (const float*)d_in[7];
    const float* ego_g     = (const float*)d_in[8];
    const float* ego_beta  = (const float*)d_in[9];
    const float* gat_w     = (const float*)d_in[10];
    const float* gat_asrc  = (const float*)d_in[11];
    const float* gat_adst  = (const float*)d_in[12];
    const float* gat_bias  = (const float*)d_in[13];
    const float* proj_w    = (const float*)d_in[14];
    const float* proj_b    = (const float*)d_in[15];

    float* out = (float*)d_out;
    float* ws  = (float*)d_ws;
    float* px   = ws + O_PX;
    float* py   = ws + O_PY;
    f16*   h16  = (f16*)(ws + O_H16);
    float* asT  = ws + O_AS;
    float* adT  = ws + O_AD;
    float* Mmax = ws + O_M;
    float* us   = ws + O_US;
    float* ud   = ws + O_UD;
    f16*   WT   = (f16*)(ws + O_WT);
    unsigned char* adj = (unsigned char*)(ws + O_ADJ);
    float* EAb  = ws + O_EA;
    float* EBb  = ws + O_EB;
    f16*   whT  = (f16*)d_out;      // 8 MB frag-order scratch in d_out; final gemm overwrites last

    node_embed<<<4096, 256, 0, stream>>>(ego, nbr, node_w, node_b, node_g, node_beta,
                                         ego_w, ego_b, ego_g, ego_beta, h16, px, py);
    adj_build<<<1024, 256, 0, stream>>>(px, py, adj);
    prep_weights<<<56, 256, 0, stream>>>(gat_w, proj_w, gat_asrc, gat_adst, WT, us, ud);
    for (int l = 0; l < 2; l++) {
        gemm_f16<<<512, 256, 0, stream>>>(h16, WT + (size_t)l * 65536, whT, nullptr, nullptr,
                                          us + l * 1024, ud + l * 1024, asT, adT);
        softmax_prep<<<64, 256, 0, stream>>>(asT, Mmax, EAb, EBb);
        gat_attn<<<512, 512, 0, stream>>>(whT, asT, adT, EAb, EBb, adj, Mmax,
                                          gat_bias + l * 256, h16);
    }
    gemm_f16<<<512, 256, 0, stream>>>(h16, WT + (size_t)2 * 65536, nullptr, out, proj_b,
                                      nullptr, nullptr, nullptr, nullptr);
    zero_mask<<<64, 256, 0, stream>>>(out + (size_t)ROWS * DIM);
}